// Round 2
// baseline (3998.625 us; speedup 1.0000x reference)
//
#include <hip/hip_runtime.h>
#include <hip/hip_bf16.h>

typedef short  bf16x8 __attribute__((ext_vector_type(8)));
typedef float  f32x4  __attribute__((ext_vector_type(4)));
typedef int    i32x2  __attribute__((ext_vector_type(2)));

#define BB 64
#define SS 512
#define EE 300
#define EP 320          // E padded to multiple of 32
#define HH 512

// workspace layout (bytes)
#define XBF_OFF    ((size_t)0)
#define XBF_BYTES  ((size_t)BB*SS*EP*2)          // 20,971,520
#define HBUF_OFF   (XBF_OFF + XBF_BYTES)
#define HBUF_BYTES ((size_t)2*BB*HH*2)           // 131,072
#define HT_OFF     (HBUF_OFF + HBUF_BYTES)
#define HT_BYTES   ((size_t)BB*HH*4)             // 131,072
#define FLAGS_OFF  (HT_OFF + HT_BYTES)
#define FLAGS_BYTES ((size_t)64*4)               // one int flag per wg

__device__ __forceinline__ unsigned short f2bf(float x) {
  union { float f; unsigned u; } v; v.f = x;
  unsigned r = v.u + 0x7fffu + ((v.u >> 16) & 1u);   // RNE
  return (unsigned short)(r >> 16);
}
__device__ __forceinline__ float sigm(float x) {       // exact, saturating, NaN-free
  return 1.f / (1.f + __expf(-x));
}
__device__ __forceinline__ float tanh_fast(float x) {  // 1 - 2/(e^2x+1), saturating
  return 1.f - 2.f / (__expf(2.f * x) + 1.f);
}

// ---- coherent (bypass L1/L2, hit Infinity Cache) access primitives ----
__device__ __forceinline__ void ld16_cc(bf16x8* dst, const void* p) {
  asm volatile("global_load_dwordx4 %0, %1, off sc0 sc1"
               : "=v"(*dst) : "v"(p) : "memory");
}
__device__ __forceinline__ int ld_flag_cc(const int* p) {
  int r;
  asm volatile("global_load_dword %0, %1, off sc0 sc1\n\ts_waitcnt vmcnt(0)"
               : "=v"(r) : "v"(p) : "memory");
  return r;
}
__device__ __forceinline__ void st8_cc(void* p, i32x2 v) {
  asm volatile("global_store_dwordx2 %0, %1, off sc0 sc1"
               :: "v"(p), "v"(v) : "memory");
}
__device__ __forceinline__ void st4_cc(void* p, int v) {
  asm volatile("global_store_dword %0, %1, off sc0 sc1"
               :: "v"(p), "v"(v) : "memory");
}

// ---- phase 0: embedding gather + cast to bf16, pad E->EP with zeros ----
__global__ void gather_cast_kernel(const int* __restrict__ idx,
                                   const float* __restrict__ emb,
                                   unsigned short* __restrict__ xbf) {
  int row = blockIdx.x;                    // b*SS + t
  int v = idx[row];
  const float* src = emb + (size_t)v * EE;
  unsigned short* dst = xbf + (size_t)row * EP;
  for (int e = threadIdx.x; e < EP; e += 64)
    dst[e] = (e < EE) ? f2bf(src[e]) : (unsigned short)0;
}

// ---- phase 1: persistent recurrence. wg p owns hidden units [8p, 8p+8). ----
// 8 waves = 4 m-tiles x 2 unit-halves; each wave carries full K=832 and
// complete i,f,g,o for (16 samples x 4 units). No fences: all cross-wg
// traffic is sc0|sc1 write-through / bypass, ordered by vmcnt(0).
__launch_bounds__(512, 2)
__global__ void lstm_kernel(const unsigned short* __restrict__ xbf,
                            unsigned short* __restrict__ hbuf,   // [2][BB][HH] bf16
                            float* __restrict__ hT,              // [BB][HH] fp32
                            int* __restrict__ flags,             // [64]
                            const float* __restrict__ Wih,
                            const float* __restrict__ Whh,
                            const float* __restrict__ bih,
                            const float* __restrict__ bhh) {
  const int p    = blockIdx.x;             // 0..63
  const int tid  = threadIdx.x;            // 0..511
  const int lane = tid & 63;
  const int w    = tid >> 6;               // 0..7
  const int mt   = w & 3;                  // m-tile: samples 16mt..16mt+15
  const int nt   = w >> 2;                 // unit-half: units 4nt..4nt+3
  const int c    = lane & 15;              // B col: gate=c>>2, unit=c&3
  const int kg   = lane >> 4;              // k-group / D row-quad

  // ---- preload W fragments (constant for all 512 steps) ----
  // B[k][n]: col n -> gate (n>>2) of global unit 8p+4nt+(n&3)
  const int Grow = ((c >> 2) << 9) + (p << 3) + (nt << 2) + (c & 3);
  const float* wih_row = Wih + (size_t)Grow * EE;
  const float* whh_row = Whh + (size_t)Grow * HH;

  bf16x8 Bx[10], Bh[16];
  #pragma unroll
  for (int ks = 0; ks < 10; ++ks) {
    int k0 = 32 * ks + 8 * kg;
    bf16x8 vb;
    #pragma unroll
    for (int j = 0; j < 8; ++j) {
      int k = k0 + j;
      vb[j] = (short)((k < EE) ? f2bf(wih_row[k]) : (unsigned short)0);
    }
    Bx[ks] = vb;
  }
  #pragma unroll
  for (int ks = 0; ks < 16; ++ks) {
    int k0 = 32 * ks + 8 * kg;
    bf16x8 vb;
    #pragma unroll
    for (int j = 0; j < 8; ++j) vb[j] = (short)f2bf(whh_row[k0 + j]);
    Bh[ks] = vb;
  }
  const float bsum = bih[Grow] + bhh[Grow];   // per-lane gate bias

  const int s0 = 16 * mt + c;                 // A row = sample
  const unsigned short* xbase = xbf + (size_t)s0 * SS * EP + 8 * kg;
  const int hread = s0 * HH + 8 * kg;

  f32x4 cst = {0.f, 0.f, 0.f, 0.f};           // cell state rows 0..3 (valid c<4)

  for (int it = 0; it < SS; ++it) {
    f32x4 acc  = {0.f, 0.f, 0.f, 0.f};
    f32x4 acc2 = {0.f, 0.f, 0.f, 0.f};

    // --- x part (plain cached loads; off the cross-wg critical path) ---
    const unsigned short* xp = xbase + (size_t)it * EP;
    #pragma unroll
    for (int ks = 0; ks < 10; ks += 2) {
      bf16x8 a0 = *(const bf16x8*)(xp + 32 * ks);
      bf16x8 a1 = *(const bf16x8*)(xp + 32 * (ks + 1));
      acc  = __builtin_amdgcn_mfma_f32_16x16x32_bf16(a0, Bx[ks],     acc,  0, 0, 0);
      acc2 = __builtin_amdgcn_mfma_f32_16x16x32_bf16(a1, Bx[ks + 1], acc2, 0, 0, 0);
    }

    // --- wait until every wg has published h(it); lane l polls flag l ---
    if (it > 0) {
      for (;;) {
        int f = ld_flag_cc(flags + lane);
        if (__all(f >= it)) break;
        __builtin_amdgcn_s_sleep(1);
      }
    }

    // --- h part: 16 coherent 16B loads, counted waits, MFMA ---
    const unsigned short* hp = hbuf + (size_t)(it & 1) * (BB * HH) + hread;
    bf16x8 ha[16];
    #pragma unroll
    for (int ks = 0; ks < 16; ++ks) ld16_cc(&ha[ks], hp + 32 * ks);

    asm volatile("s_waitcnt vmcnt(8)" ::: "memory");
    __builtin_amdgcn_sched_barrier(0);
    #pragma unroll
    for (int ks = 0; ks < 8; ks += 2) {
      acc  = __builtin_amdgcn_mfma_f32_16x16x32_bf16(ha[ks],     Bh[ks],     acc,  0, 0, 0);
      acc2 = __builtin_amdgcn_mfma_f32_16x16x32_bf16(ha[ks + 1], Bh[ks + 1], acc2, 0, 0, 0);
    }
    asm volatile("s_waitcnt vmcnt(0)" ::: "memory");
    __builtin_amdgcn_sched_barrier(0);
    #pragma unroll
    for (int ks = 8; ks < 16; ks += 2) {
      acc  = __builtin_amdgcn_mfma_f32_16x16x32_bf16(ha[ks],     Bh[ks],     acc,  0, 0, 0);
      acc2 = __builtin_amdgcn_mfma_f32_16x16x32_bf16(ha[ks + 1], Bh[ks + 1], acc2, 0, 0, 0);
    }
    acc += acc2;

    // --- gate math fully in-register: lane c holds gate c>>2 of unit c&3 ---
    unsigned short* hw = hbuf + (size_t)((it + 1) & 1) * (BB * HH);
    #pragma unroll
    for (int r = 0; r < 4; ++r) {
      float v  = acc[r] + bsum;              // own gate (biased at source lane)
      float vf = __shfl_xor(v, 4, 64);
      float vg = __shfl_xor(v, 8, 64);
      float vo = __shfl_xor(v, 12, 64);
      // valid assignment (i,f,g,o) on lanes c<4; others compute bounded garbage
      float ig = sigm(v);
      float fg = sigm(vf);
      float gt = tanh_fast(vg);
      float og = sigm(vo);
      float cc_ = fg * cst[r] + ig * gt;
      cst[r] = cc_;
      float h = og * tanh_fast(cc_);

      // pack 4 units (bf16) into 8B on lane c==0 of each 16-lane group
      int v0 = (int)f2bf(h);
      int o1 = __shfl_xor(v0, 1, 64);
      int pk = (v0 & 0xffff) | (o1 << 16);
      int o2 = __shfl_xor(pk, 2, 64);
      int s  = 16 * mt + 4 * kg + r;         // sample row
      if (c == 0) {
        i32x2 val; val[0] = pk; val[1] = o2;
        st8_cc(hw + (size_t)s * HH + (p << 3) + (nt << 2), val);
      }
      if (it == SS - 1 && c < 4) {
        hT[(size_t)s * HH + (p << 3) + (nt << 2) + c] = h;
      }
    }

    // --- publish: drain h stores, then wg flag (tid 0) ---
    asm volatile("s_waitcnt vmcnt(0)" ::: "memory");
    __syncthreads();
    if (tid == 0) st4_cc(flags + p, it + 1);
  }
}

// ---- phase 2: y[b] = hT[b,:] . Wout + bout ----
__global__ void outproj_kernel(const float* __restrict__ hT,
                               const float* __restrict__ Wout,
                               const float* __restrict__ bout,
                               float* __restrict__ y) {
  int b = blockIdx.x;
  int t = threadIdx.x;   // 64
  float s = 0.f;
  for (int j = t; j < HH; j += 64) s += hT[b * HH + j] * Wout[j];
  #pragma unroll
  for (int off = 32; off > 0; off >>= 1) s += __shfl_down(s, off, 64);
  if (t == 0) y[b] = s + bout[0];
}

extern "C" void kernel_launch(void* const* d_in, const int* in_sizes, int n_in,
                              void* d_out, int out_size, void* d_ws, size_t ws_size,
                              hipStream_t stream) {
  const int*   idx  = (const int*)d_in[0];
  const float* emb  = (const float*)d_in[1];
  const float* Wih  = (const float*)d_in[2];
  const float* Whh  = (const float*)d_in[3];
  const float* bih  = (const float*)d_in[4];
  const float* bhh  = (const float*)d_in[5];
  const float* Wout = (const float*)d_in[6];
  const float* bout = (const float*)d_in[7];
  float* y = (float*)d_out;

  char* ws = (char*)d_ws;
  unsigned short* xbf  = (unsigned short*)(ws + XBF_OFF);
  unsigned short* hbuf = (unsigned short*)(ws + HBUF_OFF);
  float* hT            = (float*)(ws + HT_OFF);
  int* flags           = (int*)(ws + FLAGS_OFF);

  // deterministic per-call init: h(0)=0 and flags=0
  hipMemsetAsync(ws + HBUF_OFF, 0, (size_t)BB * HH * 2, stream);
  hipMemsetAsync(ws + FLAGS_OFF, 0, FLAGS_BYTES, stream);

  gather_cast_kernel<<<BB * SS, 64, 0, stream>>>(idx, emb, xbf);
  lstm_kernel<<<64, 512, 0, stream>>>(xbf, hbuf, hT, flags, Wih, Whh, bih, bhh);
  outproj_kernel<<<BB, 64, 0, stream>>>(hT, Wout, bout, y);
}

// Round 3
// 2726.892 us; speedup vs baseline: 1.4664x; 1.4664x over previous
//
#include <hip/hip_runtime.h>
#include <hip/hip_bf16.h>

typedef short  bf16x8 __attribute__((ext_vector_type(8)));
typedef float  f32x4  __attribute__((ext_vector_type(4)));
typedef int    i32x2  __attribute__((ext_vector_type(2)));

#define BB 64
#define SS 512
#define EE 300
#define HH 512

// workspace layout (bytes)
#define XT_OFF     ((size_t)0)
#define XT_BYTES   ((size_t)SS*10*4*1024)        // 20,971,520  x tiles [t][ks10][mt4][1KB]
#define HBUF_OFF   (XT_OFF + XT_BYTES)
#define HBUF_BYTES ((size_t)2*BB*HH*2)           // 131,072 (double buffer)
#define HT_OFF     (HBUF_OFF + HBUF_BYTES)
#define HT_BYTES   ((size_t)BB*HH*4)             // 131,072
#define CNT_OFF    (HT_OFF + HT_BYTES)
#define CNT_BYTES  ((size_t)256)

__device__ __forceinline__ unsigned short f2bf(float x) {
  union { float f; unsigned u; } v; v.f = x;
  unsigned r = v.u + 0x7fffu + ((v.u >> 16) & 1u);   // RNE
  return (unsigned short)(r >> 16);
}
__device__ __forceinline__ float sigm(float x) { return 1.f / (1.f + __expf(-x)); }
__device__ __forceinline__ float tanh_fast(float x) { return 1.f - 2.f / (__expf(2.f * x) + 1.f); }

// ---- coherent (bypass L1/L2) access primitives ----
__device__ __forceinline__ void ld16_cc(bf16x8* dst, const void* p) {
  asm volatile("global_load_dwordx4 %0, %1, off sc0 sc1"
               : "=v"(*dst) : "v"(p) : "memory");
}
__device__ __forceinline__ int ld_flag_cc(const int* p) {
  int r;
  asm volatile("global_load_dword %0, %1, off sc0 sc1\n\ts_waitcnt vmcnt(0)"
               : "=v"(r) : "v"(p) : "memory");
  return r;
}
__device__ __forceinline__ void st8_cc(void* p, i32x2 v) {
  asm volatile("global_store_dwordx2 %0, %1, off sc0 sc1"
               :: "v"(p), "v"(v) : "memory");
}

// ---- phase 0: embedding gather + cast, fragment-tiled output ----
// out block layout: [t][ks(10)][mtile(4)] of 1KB; within block [c(16)][kg(4)][j(8)] bf16
__global__ void gather_cast_kernel(const int* __restrict__ idx,
                                   const float* __restrict__ emb,
                                   unsigned short* __restrict__ xt) {
  __shared__ unsigned short lds_x[16 * 320];
  const int t     = blockIdx.x >> 2;
  const int mtile = blockIdx.x & 3;
  const int tid   = threadIdx.x;                 // 0..255

  // fill LDS [c2][e] for 16 samples
  const int c2 = tid >> 4;
  const int e0 = tid & 15;
  const int b  = mtile * 16 + c2;
  const int vocab = idx[b * SS + t];
  const float* src = emb + (size_t)vocab * EE;
  for (int e = e0; e < 320; e += 16)
    lds_x[c2 * 320 + e] = (e < EE) ? f2bf(src[e]) : (unsigned short)0;
  __syncthreads();

  // write 10KB as coalesced 16B stores
  unsigned short* outb = xt + (((size_t)t * 10) * 4 + mtile) * 512;  // ushort units
  #pragma unroll
  for (int rr = 0; rr < 3; ++rr) {
    int O = rr * 4096 + tid * 16;                // byte offset in 10KB
    if (O < 10240) {
      int ks = O >> 10;
      int inblk = O & 1023;
      int c  = inblk >> 6;
      int kg = (inblk >> 4) & 3;
      // element k = ks*32 + kg*8 + j
      bf16x8 v = *(const bf16x8*)&lds_x[c * 320 + ks * 32 + kg * 8];
      *(bf16x8*)((char*)outb + (size_t)ks * 4096 + inblk) = v;
    }
  }
}

// ---- phase 1: persistent recurrence. wg p owns hidden units [8p, 8p+8). ----
// 8 waves = 4 m-tiles x 2 unit-halves. W in VGPRs. h staged via LDS (coalesced).
__launch_bounds__(512, 2)
__global__ void lstm_kernel(const unsigned short* __restrict__ xt,
                            unsigned short* __restrict__ hbuf,   // [2][BB][HH] bf16
                            float* __restrict__ hT,              // [BB][HH] fp32
                            int* __restrict__ cnt,               // central counter
                            const float* __restrict__ Wih,
                            const float* __restrict__ Whh,
                            const float* __restrict__ bih,
                            const float* __restrict__ bhh) {
  __shared__ char hstage[65536];   // [ks16][mt4] subtiles of 1KB, XOR-swizzled

  const int p    = blockIdx.x;             // 0..63
  const int tid  = threadIdx.x;            // 0..511
  const int l    = tid & 63;
  const int w    = tid >> 6;               // 0..7
  const int mt   = w & 3;                  // m-tile: samples 16mt..16mt+15
  const int nt   = w >> 2;                 // unit-half: units 4nt..4nt+3
  const int c    = l & 15;                 // B col: gate=c>>2, unit=c&3
  const int kg   = l >> 4;                 // k-group

  // ---- preload W fragments (constant all 512 steps) ----
  const int Grow = ((c >> 2) << 9) + (p << 3) + (nt << 2) + (c & 3);
  const float* wih_row = Wih + (size_t)Grow * EE;
  const float* whh_row = Whh + (size_t)Grow * HH;

  bf16x8 Bx[10], Bh[16];
  #pragma unroll
  for (int ks = 0; ks < 10; ++ks) {
    int k0 = 32 * ks + 8 * kg;
    bf16x8 vb;
    #pragma unroll
    for (int j = 0; j < 8; ++j) {
      int k = k0 + j;
      vb[j] = (short)((k < EE) ? f2bf(wih_row[k]) : (unsigned short)0);
    }
    Bx[ks] = vb;
  }
  #pragma unroll
  for (int ks = 0; ks < 16; ++ks) {
    int k0 = 32 * ks + 8 * kg;
    bf16x8 vb;
    #pragma unroll
    for (int j = 0; j < 8; ++j) vb[j] = (short)f2bf(whh_row[k0 + j]);
    Bh[ks] = vb;
  }
  const float bsum = bih[Grow] + bhh[Grow];

  // x fragment base (ushort units): block ((it*10+ks)*4 + mt), inblock (c,kg)
  const int xoff = (c << 5) + (kg << 3);
  // stage decode (constant per thread): ks_s = l>>2, slot = (l&3)*16
  const int ks_s   = l >> 2;
  const int slot_s = (l & 3) << 4;
  // fragment-read address pieces
  const int frag_in = (c << 6) + (kg << 4);

  f32x4 cst = {0.f, 0.f, 0.f, 0.f};

  for (int it = 0; it < SS; ++it) {
    f32x4 acc  = {0.f, 0.f, 0.f, 0.f};
    f32x4 acc2 = {0.f, 0.f, 0.f, 0.f};

    // --- x part (plain cached loads, coalesced 1KB per instr; overlaps wait) ---
    const unsigned short* xq = xt + (((size_t)it * 10) * 4 + mt) * 512 + xoff;
    #pragma unroll
    for (int ks = 0; ks < 10; ks += 2) {
      bf16x8 a0 = *(const bf16x8*)(xq + (size_t)ks * 2048);
      bf16x8 a1 = *(const bf16x8*)(xq + (size_t)(ks + 1) * 2048);
      acc  = __builtin_amdgcn_mfma_f32_16x16x32_bf16(a0, Bx[ks],     acc,  0, 0, 0);
      acc2 = __builtin_amdgcn_mfma_f32_16x16x32_bf16(a1, Bx[ks + 1], acc2, 0, 0, 0);
    }

    // --- wait for all wgs to publish h(it): single-lane poll on central counter ---
    if (tid == 0) {
      const int target = 64 * it;
      while (ld_flag_cc(cnt) < target) __builtin_amdgcn_s_sleep(1);
    }
    __syncthreads();

    // --- stage h(it) into LDS: coalesced coherent loads, swizzled subtiled writes ---
    {
      const char* hsrc = (const char*)hbuf + (size_t)(it & 1) * (BB * HH * 2);
      bf16x8 sb[8];
      #pragma unroll
      for (int r = 0; r < 8; ++r) ld16_cc(&sb[r], hsrc + r * 8192 + tid * 16);
      asm volatile("s_waitcnt vmcnt(0)" ::: "memory");
      __builtin_amdgcn_sched_barrier(0);
      #pragma unroll
      for (int r = 0; r < 8; ++r) {
        int sample = r * 8 + w;
        int mtile  = sample >> 4;
        int cc     = sample & 15;
        int addr   = (((ks_s << 2) + mtile) << 10) + (cc << 6) + slot_s;
        addr ^= (ks_s & 7) << 4;
        *(bf16x8*)(hstage + addr) = sb[r];
      }
    }
    __syncthreads();

    // --- h part: conflict-optimal ds_read_b128 fragments + MFMA ---
    #pragma unroll
    for (int ks = 0; ks < 16; ks += 2) {
      int a0addr = ((((ks)     << 2) + mt) << 10) + frag_in; a0addr ^= ((ks)     & 7) << 4;
      int a1addr = ((((ks + 1) << 2) + mt) << 10) + frag_in; a1addr ^= ((ks + 1) & 7) << 4;
      bf16x8 a0 = *(const bf16x8*)(hstage + a0addr);
      bf16x8 a1 = *(const bf16x8*)(hstage + a1addr);
      acc  = __builtin_amdgcn_mfma_f32_16x16x32_bf16(a0, Bh[ks],     acc,  0, 0, 0);
      acc2 = __builtin_amdgcn_mfma_f32_16x16x32_bf16(a1, Bh[ks + 1], acc2, 0, 0, 0);
    }
    acc += acc2;

    // --- gate math in-register: lane c holds gate c>>2 of unit c&3 ---
    unsigned short* hw = hbuf + (size_t)((it + 1) & 1) * (BB * HH);
    #pragma unroll
    for (int r = 0; r < 4; ++r) {
      float v  = acc[r] + bsum;
      float vf = __shfl_xor(v, 4, 64);
      float vg = __shfl_xor(v, 8, 64);
      float vo = __shfl_xor(v, 12, 64);
      float ig = sigm(v);
      float fg = sigm(vf);
      float gt = tanh_fast(vg);
      float og = sigm(vo);
      float cc_ = fg * cst[r] + ig * gt;
      cst[r] = cc_;
      float h = og * tanh_fast(cc_);

      int v0 = (int)f2bf(h);
      int o1 = __shfl_xor(v0, 1, 64);
      int pk = (v0 & 0xffff) | (o1 << 16);
      int o2 = __shfl_xor(pk, 2, 64);
      int s  = 16 * mt + 4 * kg + r;
      if (c == 0) {
        i32x2 val; val[0] = pk; val[1] = o2;
        st8_cc(hw + (size_t)s * HH + (p << 3) + (nt << 2), val);
      }
      if (it == SS - 1 && c < 4) {
        hT[(size_t)s * HH + (p << 3) + (nt << 2) + c] = h;
      }
    }

    // --- publish: drain own stores, barrier, one atomicAdd per wg ---
    asm volatile("s_waitcnt vmcnt(0)" ::: "memory");
    __syncthreads();
    if (tid == 0)
      __hip_atomic_fetch_add(cnt, 1, __ATOMIC_RELAXED, __HIP_MEMORY_SCOPE_AGENT);
  }
}

// ---- phase 2: y[b] = hT[b,:] . Wout + bout ----
__global__ void outproj_kernel(const float* __restrict__ hT,
                               const float* __restrict__ Wout,
                               const float* __restrict__ bout,
                               float* __restrict__ y) {
  int b = blockIdx.x;
  int t = threadIdx.x;   // 64
  float s = 0.f;
  for (int j = t; j < HH; j += 64) s += hT[b * HH + j] * Wout[j];
  #pragma unroll
  for (int off = 32; off > 0; off >>= 1) s += __shfl_down(s, off, 64);
  if (t == 0) y[b] = s + bout[0];
}

extern "C" void kernel_launch(void* const* d_in, const int* in_sizes, int n_in,
                              void* d_out, int out_size, void* d_ws, size_t ws_size,
                              hipStream_t stream) {
  const int*   idx  = (const int*)d_in[0];
  const float* emb  = (const float*)d_in[1];
  const float* Wih  = (const float*)d_in[2];
  const float* Whh  = (const float*)d_in[3];
  const float* bih  = (const float*)d_in[4];
  const float* bhh  = (const float*)d_in[5];
  const float* Wout = (const float*)d_in[6];
  const float* bout = (const float*)d_in[7];
  float* y = (float*)d_out;

  char* ws = (char*)d_ws;
  unsigned short* xt   = (unsigned short*)(ws + XT_OFF);
  unsigned short* hbuf = (unsigned short*)(ws + HBUF_OFF);
  float* hT            = (float*)(ws + HT_OFF);
  int* cnt             = (int*)(ws + CNT_OFF);

  // deterministic per-call init: h(0)=0 and cnt=0
  hipMemsetAsync(ws + HBUF_OFF, 0, (size_t)BB * HH * 2, stream);
  hipMemsetAsync(ws + CNT_OFF, 0, CNT_BYTES, stream);

  gather_cast_kernel<<<SS * 4, 256, 0, stream>>>(idx, emb, xt);
  lstm_kernel<<<64, 512, 0, stream>>>(xt, hbuf, hT, cnt, Wih, Whh, bih, bhh);
  outproj_kernel<<<BB, 64, 0, stream>>>(hT, Wout, bout, y);
}